// Round 2
// baseline (438.698 us; speedup 1.0000x reference)
//
#include <hip/hip_runtime.h>

// SSIM (16,3,512,512) f32. Fused separable 11x11 Gaussian convs + SSIM + mean.
// R2: register-blocked conv passes (4 outputs/thread each dir), float4-packed
// LDS fields, v_rcp for the divide, single kernel + memset (last-block final).

#define KSZ   11
#define PAD   5
#define TILE  32
#define HALO  (TILE + KSZ - 1)   // 42
#define SXW   44                 // padded sx row stride (floats), 176B = mult of 16
#define NT    256
#define NBX   (512 / TILE)
#define NBY   (512 / TILE)
#define NPLANES 48
#define NBLOCKS (NBX * NBY * NPLANES)

static __device__ __forceinline__ float fast_rcp(float x) {
#if __has_builtin(__builtin_amdgcn_rcpf)
    return __builtin_amdgcn_rcpf(x);
#else
    return 1.0f / x;
#endif
}

__global__ __launch_bounds__(NT)
void ssim_fused(const float* __restrict__ img1,
                const float* __restrict__ img2,
                const float* __restrict__ window,
                double* __restrict__ acc,
                unsigned int* __restrict__ counter,
                float* __restrict__ out)
{
    __shared__ float k1d[KSZ];
    __shared__ __align__(16) float sx1[HALO * SXW];
    __shared__ __align__(16) float sx2[HALO * SXW];
    __shared__ float4 hA[HALO * TILE];   // (h0,h1,h2,h3) packed
    __shared__ float  hB[HALO * TILE];   // h4
    __shared__ float red[NT / 64];

    const int tid = threadIdx.x;
    const int bx = blockIdx.x * TILE;
    const int by = blockIdx.y * TILE;
    const size_t planeOff = (size_t)blockIdx.z * 512 * 512;
    const float* p1 = img1 + planeOff;
    const float* p2 = img2 + planeOff;

    // 1D kernel = row sums of the 2D window (window = outer(k,k), sum(k)=1).
    if (tid < KSZ) {
        float s = 0.f;
        #pragma unroll
        for (int j = 0; j < KSZ; ++j) s += window[tid * KSZ + j];
        k1d[tid] = s;
    }

    // Stage raw halo tiles (zero outside image = zero padding). Stride SXW=44;
    // cols 42,43 stay stale but are never consumed by the unrolled taps.
    for (int idx = tid; idx < HALO * HALO; idx += NT) {
        const int r = idx / HALO;
        const int c = idx - r * HALO;
        const int gr = by + r - PAD;
        const int gc = bx + c - PAD;
        float v1 = 0.f, v2 = 0.f;
        if (((unsigned)gr < 512u) && ((unsigned)gc < 512u)) {
            const size_t g = (size_t)gr * 512 + gc;
            v1 = p1[g];
            v2 = p2[g];
        }
        sx1[r * SXW + c] = v1;
        sx2[r * SXW + c] = v2;
    }
    __syncthreads();

    float wk[KSZ];
    #pragma unroll
    for (int k = 0; k < KSZ; ++k) wk[k] = k1d[k];

    // ---- Horizontal pass: thread = (row, 4-col group), sliding window in regs.
    {
        const int hcg = tid & 7;         // float4 col group, c0 = 4*hcg
        const int hr0 = tid >> 3;        // 0..31
        #pragma unroll
        for (int rr = 0; rr < 2; ++rr) {
            const int r = hr0 + rr * 32;
            if (r < HALO) {
                const float4* r1 = (const float4*)(sx1 + r * SXW);
                const float4* r2 = (const float4*)(sx2 + r * SXW);
                const float4 A0 = r1[hcg], A1 = r1[hcg + 1], A2 = r1[hcg + 2], A3 = r1[hcg + 3];
                const float4 B0 = r2[hcg], B1 = r2[hcg + 1], B2 = r2[hcg + 2], B3 = r2[hcg + 3];
                const float x1v[16] = {A0.x,A0.y,A0.z,A0.w, A1.x,A1.y,A1.z,A1.w,
                                       A2.x,A2.y,A2.z,A2.w, A3.x,A3.y,A3.z,A3.w};
                const float x2v[16] = {B0.x,B0.y,B0.z,B0.w, B1.x,B1.y,B1.z,B1.w,
                                       B2.x,B2.y,B2.z,B2.w, B3.x,B3.y,B3.z,B3.w};
                float q1[14], q2[14], q12[14];
                #pragma unroll
                for (int i = 0; i < 14; ++i) {
                    q1[i]  = x1v[i] * x1v[i];
                    q2[i]  = x2v[i] * x2v[i];
                    q12[i] = x1v[i] * x2v[i];
                }
                float h0[4] = {0,0,0,0}, h1[4] = {0,0,0,0}, h2[4] = {0,0,0,0},
                      h3[4] = {0,0,0,0}, h4[4] = {0,0,0,0};
                #pragma unroll
                for (int k = 0; k < KSZ; ++k) {
                    const float w = wk[k];
                    #pragma unroll
                    for (int c = 0; c < 4; ++c) {
                        h0[c] += w * x1v[c + k];
                        h1[c] += w * x2v[c + k];
                        h2[c] += w * q1[c + k];
                        h3[c] += w * q2[c + k];
                        h4[c] += w * q12[c + k];
                    }
                }
                const int base = r * TILE + hcg * 4;
                #pragma unroll
                for (int c = 0; c < 4; ++c) {
                    hA[base + c] = make_float4(h0[c], h1[c], h2[c], h3[c]);
                    hB[base + c] = h4[c];
                }
            }
        }
    }
    __syncthreads();

    // ---- Vertical pass: thread = (col, 4-row group). 14 packed rows -> 4 outputs.
    const float C1f = 1e-4f;
    const float C2f = 9e-4f;
    float lsum = 0.f;
    {
        const int vc  = tid & 31;
        const int vr0 = (tid >> 5) * 4;   // 0..28
        float av[4][5];
        #pragma unroll
        for (int i = 0; i < 4; ++i)
            #pragma unroll
            for (int f = 0; f < 5; ++f) av[i][f] = 0.f;

        #pragma unroll
        for (int j = 0; j < TILE - TILE + 14; ++j) {  // 14 rows
            const int hr = vr0 + j;
            const float4 va = hA[hr * TILE + vc];
            const float  vb = hB[hr * TILE + vc];
            #pragma unroll
            for (int i = 0; i < 4; ++i) {
                const int k = j - i;
                if (k >= 0 && k < KSZ) {
                    const float w = wk[k];
                    av[i][0] += w * va.x;
                    av[i][1] += w * va.y;
                    av[i][2] += w * va.z;
                    av[i][3] += w * va.w;
                    av[i][4] += w * vb;
                }
            }
        }
        #pragma unroll
        for (int i = 0; i < 4; ++i) {
            const float mu1 = av[i][0], mu2 = av[i][1];
            const float e11 = av[i][2], e22 = av[i][3], e12 = av[i][4];
            const float mu1sq = mu1 * mu1;
            const float mu2sq = mu2 * mu2;
            const float mu12  = mu1 * mu2;
            const float s11 = e11 - mu1sq;
            const float s22 = e22 - mu2sq;
            const float s12 = e12 - mu12;
            const float num = (2.f * mu12 + C1f) * (2.f * s12 + C2f);
            const float den = (mu1sq + mu2sq + C1f) * (s11 + s22 + C2f);
            lsum += num * fast_rcp(den);
        }
    }

    // ---- Block reduction, then one device atomic; last block finalizes.
    #pragma unroll
    for (int off = 32; off > 0; off >>= 1)
        lsum += __shfl_down(lsum, off, 64);
    const int wave = tid >> 6;
    const int lane = tid & 63;
    if (lane == 0) red[wave] = lsum;
    __syncthreads();
    if (tid == 0) {
        float bsum = red[0] + red[1] + red[2] + red[3];
        atomicAdd(acc, (double)bsum);
        __threadfence();
        const unsigned prev = atomicAdd(counter, 1u);
        if (prev == (unsigned)(NBLOCKS - 1)) {
            __threadfence();
            const double total = atomicAdd(acc, 0.0);
            out[0] = (float)(total * (1.0 / ((double)NBLOCKS * TILE * TILE)));
        }
    }
}

extern "C" void kernel_launch(void* const* d_in, const int* in_sizes, int n_in,
                              void* d_out, int out_size, void* d_ws, size_t ws_size,
                              hipStream_t stream) {
    const float* img1   = (const float*)d_in[0];
    const float* img2   = (const float*)d_in[1];
    const float* window = (const float*)d_in[2];
    float* out = (float*)d_out;
    double* acc = (double*)d_ws;
    unsigned int* counter = (unsigned int*)((char*)d_ws + 8);

    hipMemsetAsync(d_ws, 0, 16, stream);

    dim3 grid(NBX, NBY, NPLANES);
    ssim_fused<<<grid, NT, 0, stream>>>(img1, img2, window, acc, counter, out);
}